// Round 5
// baseline (287.758 us; speedup 1.0000x reference)
//
#include <hip/hip_runtime.h>
#include <hip/hip_bf16.h>

typedef __bf16 bf16_t;
typedef bf16_t bf16x8 __attribute__((ext_vector_type(8)));
typedef bf16_t bf16x4 __attribute__((ext_vector_type(4)));
typedef float  f32x4  __attribute__((ext_vector_type(4)));

constexpr int B_ = 8, C_ = 512, HW_ = 4096, LC_ = 512, CTX_ = 768;

// ---------- prep kernels ----------

__global__ void k_transpose_w(const float* __restrict__ in, bf16_t* __restrict__ out,
                              int R, int Cc) {
    __shared__ float t[32][33];
    int r0 = blockIdx.x * 32, c0 = blockIdx.y * 32;
    int tx = threadIdx.x, ty = threadIdx.y;  // 32 x 8
#pragma unroll
    for (int i = 0; i < 4; ++i)
        t[ty + i * 8][tx] = in[(size_t)(r0 + ty + i * 8) * Cc + c0 + tx];
    __syncthreads();
#pragma unroll
    for (int i = 0; i < 4; ++i)
        out[(size_t)(c0 + ty + i * 8) * R + r0 + tx] = (bf16_t)t[tx][ty + i * 8];
}

__global__ void k_bvo(const float* __restrict__ bv, const float* __restrict__ Wo,
                      const float* __restrict__ bo, float* __restrict__ bvo) {
    int c = blockIdx.x * 256 + threadIdx.x;
    if (c >= C_) return;
    float s = bo[c];
    for (int m = 0; m < C_; ++m) s += bv[m] * Wo[(size_t)m * C_ + c];
    bvo[c] = s;
}

__global__ void k_f32_to_bf16(const float* __restrict__ in, bf16_t* __restrict__ out, int n) {
    int i = (blockIdx.x * 256 + threadIdx.x) * 4;
    if (i >= n) return;
    f32x4 v = *(const f32x4*)(in + i);
    bf16x4 w;
    w[0] = (bf16_t)v.x; w[1] = (bf16_t)v.y; w[2] = (bf16_t)v.z; w[3] = (bf16_t)v.w;
    *(bf16x4*)(out + i) = w;
}

// x [B][C][HW] f32  ->  xt [B][HW][C] bf16
__global__ void k_transpose_x(const float* __restrict__ x, bf16_t* __restrict__ xt) {
    __shared__ float t[32][33];
    int b = blockIdx.z;
    int p0 = blockIdx.x * 32, c0 = blockIdx.y * 32;
    const float* xb = x + (size_t)b * C_ * HW_;
    bf16_t* xtb = xt + (size_t)b * HW_ * C_;
    int tx = threadIdx.x, ty = threadIdx.y;  // 32 x 8
#pragma unroll
    for (int i = 0; i < 4; ++i) {
        int c = c0 + ty + i * 8;
        t[ty + i * 8][tx] = xb[(size_t)c * HW_ + p0 + tx];
    }
    __syncthreads();
#pragma unroll
    for (int i = 0; i < 4; ++i) {
        int p = p0 + ty + i * 8;
        xtb[(size_t)p * C_ + c0 + tx] = (bf16_t)t[tx][ty + i * 8];
    }
}

// ---------- projection GEMM (proven round-2 structure) ----------
// MODE 0: out bf16 [M][N], val = acc*scale + bias[n]
// MODE 1: out bf16 V^T layout: r -> (b=r>>9, l=r&511), out[b][n][l] = acc + bias[n]
// MODE 3: out bf16 transposed [N][Mtot], Mtot passed in sOut: out[n][m] = acc
template <int MODE>
__global__ __launch_bounds__(256) void k_gemm(
    const bf16_t* __restrict__ A, int lda, long sA,
    const bf16_t* __restrict__ Bt, int ldb, long sB,
    const float* __restrict__ bias,
    void* __restrict__ out_, long sOut,
    int N, int K, float scale) {
    __shared__ bf16_t lA[128 * 32];
    __shared__ bf16_t lB[128 * 32];
    const int z = blockIdx.z;
    A  += (size_t)z * sA;
    Bt += (size_t)z * sB;
    const int tid  = threadIdx.x;
    const int lane = tid & 63;
    const int wave = tid >> 6;
    const int wm = (wave >> 1) * 64, wn = (wave & 1) * 64;
    const int bm0 = blockIdx.y * 128, bn0 = blockIdx.x * 128;
    const int ar = lane & 15, kc = lane >> 4;

    auto lA3 = (__attribute__((address_space(3))) char*)&lA[0];
    auto lB3 = (__attribute__((address_space(3))) char*)&lB[0];

    f32x4 acc[4][4] = {};

    for (int k0 = 0; k0 < K; k0 += 32) {
        __syncthreads();
#pragma unroll
        for (int s = 0; s < 2; ++s) {
            int wchunk = wave * 2 + s;
            int id = wchunk * 64 + lane;
            int row = id >> 2, c4 = id & 3;
            __builtin_amdgcn_global_load_lds(
                (const __attribute__((address_space(1))) void*)
                    &A[(size_t)(bm0 + row) * lda + k0 + c4 * 8],
                (__attribute__((address_space(3))) void*)(lA3 + wchunk * 1024),
                16, 0, 0);
            __builtin_amdgcn_global_load_lds(
                (const __attribute__((address_space(1))) void*)
                    &Bt[(size_t)(bn0 + row) * ldb + k0 + c4 * 8],
                (__attribute__((address_space(3))) void*)(lB3 + wchunk * 1024),
                16, 0, 0);
        }
        __syncthreads();
        bf16x8 af[4], bfr[4];
#pragma unroll
        for (int f = 0; f < 4; ++f) {
            af[f]  = *(const bf16x8*)&lA[(wm + f * 16 + ar) * 32 + kc * 8];
            bfr[f] = *(const bf16x8*)&lB[(wn + f * 16 + ar) * 32 + kc * 8];
        }
#pragma unroll
        for (int fm = 0; fm < 4; ++fm)
#pragma unroll
            for (int fn = 0; fn < 4; ++fn)
                acc[fm][fn] = __builtin_amdgcn_mfma_f32_16x16x32_bf16(
                    af[fm], bfr[fn], acc[fm][fn], 0, 0, 0);
    }

    const int rj = (lane >> 4) * 4;
    const int cj = lane & 15;

#pragma unroll
    for (int fm = 0; fm < 4; ++fm) {
#pragma unroll
        for (int fn = 0; fn < 4; ++fn) {
            int r0 = bm0 + wm + fm * 16 + rj;
            int cc = bn0 + wn + fn * 16 + cj;
            if constexpr (MODE == 0) {
                bf16_t* out = (bf16_t*)out_ + (size_t)z * sOut;
                float bb = bias ? bias[cc] : 0.f;
#pragma unroll
                for (int j = 0; j < 4; ++j)
                    out[(size_t)(r0 + j) * N + cc] = (bf16_t)(acc[fm][fn][j] * scale + bb);
            } else if constexpr (MODE == 1) {
                bf16_t* out = (bf16_t*)out_;
                int b = r0 >> 9, l0 = r0 & 511;
                float bb = bias[cc];
                bf16x4 v;
#pragma unroll
                for (int j = 0; j < 4; ++j) v[j] = (bf16_t)(acc[fm][fn][j] + bb);
                *(bf16x4*)&out[(size_t)b * C_ * LC_ + (size_t)cc * LC_ + l0] = v;
            } else {  // MODE 3
                bf16_t* out = (bf16_t*)out_;
                bf16x4 v;
#pragma unroll
                for (int j = 0; j < 4; ++j) v[j] = (bf16_t)acc[fm][fn][j];
                *(bf16x4*)&out[(size_t)cc * sOut + r0] = v;
            }
        }
    }
}

// ---------- fused flash attention ----------
// Per block: 64 Q-rows x full Lc=512. QK^T -> softmax -> PV -> residual store.
// Q-tile in LDS (swizzled); K/V fragments read directly from L2-resident global.
// grid = 512 blocks of 512 threads; z = bid&7 pins each batch to one XCD.
__global__ __launch_bounds__(512, 2) void k_flash(
    const bf16_t* __restrict__ Qb, const bf16_t* __restrict__ Kb,
    const bf16_t* __restrict__ Vt, const float* __restrict__ x,
    float* __restrict__ out) {
    __shared__ bf16_t lQP[64 * 512];     // Q tile, later reused as P tile (64 KB)
    __shared__ float redmax[4][64];
    __shared__ float redsum[4][64];

    const int bid = blockIdx.x;
    const int z = bid & 7;
    const int q0 = (bid >> 3) * 64;
    const int tid = threadIdx.x;
    const int lane = tid & 63;
    const int wave = tid >> 6;
    const int wm2 = wave >> 2;   // 0..1  (32-row group)
    const int wn4 = wave & 3;    // 0..3  (128-col group)
    const int h = lane >> 4;     // 0..3
    const int r15 = lane & 15;

    const bf16_t* Qz = Qb + ((size_t)z * HW_ + q0) * C_;
    const bf16_t* Kz = Kb + (size_t)z * LC_ * C_;
    const bf16_t* Vz = Vt + (size_t)z * C_ * LC_;

    auto lQ3 = (__attribute__((address_space(3))) char*)&lQP[0];

    // ---- stage Q tile (64x512 bf16), source pre-swizzled so LDS dest is linear ----
#pragma unroll
    for (int t = 0; t < 8; ++t) {
        int row = wave * 8 + t;
        int c16 = (lane & 56) | ((lane ^ row) & 7);
        __builtin_amdgcn_global_load_lds(
            (const __attribute__((address_space(1))) void*)&Qz[(size_t)row * C_ + c16 * 8],
            (__attribute__((address_space(3))) void*)(lQ3 + row * 1024),
            16, 0, 0);
    }
    __syncthreads();

    // ---- QK^T : acc[m][n], rows wm2*32+m*16+(h*4+j), cols wn4*128+n*16+r15 ----
    f32x4 acc[2][8] = {};
    {
        bf16x8 bf[2][8], af[2][2];
#pragma unroll
        for (int n = 0; n < 8; ++n) {
            int col = wn4 * 128 + n * 16 + r15;
            bf[0][n] = *(const bf16x8*)&Kz[(size_t)col * C_ + h * 8];
        }
#pragma unroll
        for (int m = 0; m < 2; ++m) {
            int row = wm2 * 32 + m * 16 + r15;
            int sc = (h & 56) | ((h ^ row) & 7);
            af[0][m] = *(const bf16x8*)&lQP[row * 512 + sc * 8];
        }
#pragma unroll
        for (int kk = 0; kk < 16; ++kk) {
            const int cur = kk & 1, nxt = cur ^ 1;
            if (kk < 15) {
                int k = (kk + 1) * 32 + h * 8;
#pragma unroll
                for (int n = 0; n < 8; ++n) {
                    int col = wn4 * 128 + n * 16 + r15;
                    bf[nxt][n] = *(const bf16x8*)&Kz[(size_t)col * C_ + k];
                }
                int c16 = (kk + 1) * 4 + h;
#pragma unroll
                for (int m = 0; m < 2; ++m) {
                    int row = wm2 * 32 + m * 16 + r15;
                    int sc = (c16 & 56) | ((c16 ^ row) & 7);
                    af[nxt][m] = *(const bf16x8*)&lQP[row * 512 + sc * 8];
                }
            }
#pragma unroll
            for (int m = 0; m < 2; ++m)
#pragma unroll
                for (int n = 0; n < 8; ++n)
                    acc[m][n] = __builtin_amdgcn_mfma_f32_16x16x32_bf16(
                        af[cur][m], bf[cur][n], acc[m][n], 0, 0, 0);
        }
    }

    // ---- softmax over full rows (Lc=512) ----
    const float scale = 0.044194173824159216f;  // 512^-0.5
    float M[2][4], inv[2][4];
#pragma unroll
    for (int m = 0; m < 2; ++m)
#pragma unroll
        for (int j = 0; j < 4; ++j) {
            float v = -1e30f;
#pragma unroll
            for (int n = 0; n < 8; ++n) v = fmaxf(v, acc[m][n][j]);
#pragma unroll
            for (int o = 1; o < 16; o <<= 1) v = fmaxf(v, __shfl_xor(v, o));
            if (r15 == 0) redmax[wn4][wm2 * 32 + m * 16 + h * 4 + j] = v;
        }
    __syncthreads();
#pragma unroll
    for (int m = 0; m < 2; ++m)
#pragma unroll
        for (int j = 0; j < 4; ++j) {
            int row = wm2 * 32 + m * 16 + h * 4 + j;
            M[m][j] = fmaxf(fmaxf(redmax[0][row], redmax[1][row]),
                            fmaxf(redmax[2][row], redmax[3][row]));
        }
#pragma unroll
    for (int m = 0; m < 2; ++m)
#pragma unroll
        for (int j = 0; j < 4; ++j) {
            float s = 0.f;
#pragma unroll
            for (int n = 0; n < 8; ++n) {
                float e = __expf((acc[m][n][j] - M[m][j]) * scale);
                acc[m][n][j] = e;
                s += e;
            }
#pragma unroll
            for (int o = 1; o < 16; o <<= 1) s += __shfl_xor(s, o);
            if (r15 == 0) redsum[wn4][wm2 * 32 + m * 16 + h * 4 + j] = s;
        }
    __syncthreads();
#pragma unroll
    for (int m = 0; m < 2; ++m)
#pragma unroll
        for (int j = 0; j < 4; ++j) {
            int row = wm2 * 32 + m * 16 + h * 4 + j;
            inv[m][j] = 1.f / (redsum[0][row] + redsum[1][row] +
                               redsum[2][row] + redsum[3][row]);
        }
    __syncthreads();   // all QK reads of lQP done block-wide; reuse as P

    // ---- write P (bf16, swizzled) into lQP ----
#pragma unroll
    for (int m = 0; m < 2; ++m)
#pragma unroll
        for (int j = 0; j < 4; ++j) {
            int row = wm2 * 32 + m * 16 + h * 4 + j;
#pragma unroll
            for (int n = 0; n < 8; ++n) {
                int col = wn4 * 128 + n * 16 + r15;
                int c16 = col >> 3;
                int sc = (c16 & 56) | ((c16 ^ row) & 7);
                lQP[row * 512 + sc * 8 + (col & 7)] = (bf16_t)(acc[m][n][j] * inv[m][j]);
            }
        }
    __syncthreads();

    // ---- PV: O[row q][col c] = sum_kv P * Vt[c][kv] ----
    f32x4 oacc[2][8] = {};
    {
        bf16x8 vf[2][8], pf[2][2];
#pragma unroll
        for (int n = 0; n < 8; ++n) {
            int col = wn4 * 128 + n * 16 + r15;
            vf[0][n] = *(const bf16x8*)&Vz[(size_t)col * LC_ + h * 8];
        }
#pragma unroll
        for (int m = 0; m < 2; ++m) {
            int row = wm2 * 32 + m * 16 + r15;
            int sc = (h & 56) | ((h ^ row) & 7);
            pf[0][m] = *(const bf16x8*)&lQP[row * 512 + sc * 8];
        }
#pragma unroll
        for (int kk = 0; kk < 16; ++kk) {
            const int cur = kk & 1, nxt = cur ^ 1;
            if (kk < 15) {
                int k = (kk + 1) * 32 + h * 8;
#pragma unroll
                for (int n = 0; n < 8; ++n) {
                    int col = wn4 * 128 + n * 16 + r15;
                    vf[nxt][n] = *(const bf16x8*)&Vz[(size_t)col * LC_ + k];
                }
                int c16 = (kk + 1) * 4 + h;
#pragma unroll
                for (int m = 0; m < 2; ++m) {
                    int row = wm2 * 32 + m * 16 + r15;
                    int sc = (c16 & 56) | ((c16 ^ row) & 7);
                    pf[nxt][m] = *(const bf16x8*)&lQP[row * 512 + sc * 8];
                }
            }
#pragma unroll
            for (int m = 0; m < 2; ++m)
#pragma unroll
                for (int n = 0; n < 8; ++n)
                    oacc[m][n] = __builtin_amdgcn_mfma_f32_16x16x32_bf16(
                        pf[cur][m], vf[cur][n], oacc[m][n], 0, 0, 0);
        }
    }

    // ---- epilogue: out[c][hw] = O + x[c][hw] ----
    float* oz = out + (size_t)z * C_ * HW_;
    const float* xz = x + (size_t)z * C_ * HW_;
#pragma unroll
    for (int m = 0; m < 2; ++m)
#pragma unroll
        for (int n = 0; n < 8; ++n) {
            int r0 = q0 + wm2 * 32 + m * 16 + h * 4;
            int cc = wn4 * 128 + n * 16 + r15;
            f32x4 xv = *(const f32x4*)&xz[(size_t)cc * HW_ + r0];
            f32x4 o;
#pragma unroll
            for (int j = 0; j < 4; ++j) o[j] = oacc[m][n][j] + xv[j];
            *(f32x4*)&oz[(size_t)cc * HW_ + r0] = o;
        }
}

extern "C" void kernel_launch(void* const* d_in, const int* in_sizes, int n_in,
                              void* d_out, int out_size, void* d_ws, size_t ws_size,
                              hipStream_t stream) {
    (void)in_sizes; (void)n_in; (void)out_size; (void)ws_size;
    const float* x   = (const float*)d_in[0];
    const float* ctx = (const float*)d_in[1];
    const float* Wq  = (const float*)d_in[2];
    const float* bq  = (const float*)d_in[3];
    const float* Wk  = (const float*)d_in[4];
    const float* bk  = (const float*)d_in[5];
    const float* Wv  = (const float*)d_in[6];
    const float* bv  = (const float*)d_in[7];
    const float* Wo  = (const float*)d_in[8];
    const float* bo  = (const float*)d_in[9];
    float* out = (float*)d_out;

    char* ws = (char*)d_ws;
    size_t off = 0;
    auto alloc = [&](size_t bytes) {
        char* p = ws + off;
        off += (bytes + 255) & ~(size_t)255;
        return p;
    };
    bf16_t* Wq_t  = (bf16_t*)alloc((size_t)C_ * C_ * 2);
    bf16_t* Wk_t  = (bf16_t*)alloc((size_t)C_ * CTX_ * 2);
    bf16_t* Wvo_t = (bf16_t*)alloc((size_t)C_ * CTX_ * 2);
    bf16_t* Wv_b  = (bf16_t*)alloc((size_t)CTX_ * C_ * 2);
    bf16_t* Wo_t  = (bf16_t*)alloc((size_t)C_ * C_ * 2);
    float*  bvo   = (float*)alloc((size_t)C_ * 4);
    bf16_t* ctxb  = (bf16_t*)alloc((size_t)B_ * LC_ * CTX_ * 2);
    bf16_t* xt    = (bf16_t*)alloc((size_t)B_ * HW_ * C_ * 2);
    bf16_t* Qb    = (bf16_t*)alloc((size_t)B_ * HW_ * C_ * 2);
    bf16_t* Kb    = (bf16_t*)alloc((size_t)B_ * LC_ * C_ * 2);
    bf16_t* Vt    = (bf16_t*)alloc((size_t)B_ * C_ * LC_ * 2);

    // weight prep
    k_transpose_w<<<dim3(C_ / 32, C_ / 32), dim3(32, 8), 0, stream>>>(Wq, Wq_t, C_, C_);
    k_transpose_w<<<dim3(CTX_ / 32, C_ / 32), dim3(32, 8), 0, stream>>>(Wk, Wk_t, CTX_, C_);
    k_transpose_w<<<dim3(C_ / 32, C_ / 32), dim3(32, 8), 0, stream>>>(Wo, Wo_t, C_, C_);
    k_f32_to_bf16<<<(CTX_ * C_ / 4 + 255) / 256, 256, 0, stream>>>(Wv, Wv_b, CTX_ * C_);
    k_bvo<<<2, 256, 0, stream>>>(bv, Wo, bo, bvo);
    k_f32_to_bf16<<<(B_ * LC_ * CTX_ / 4 + 255) / 256, 256, 0, stream>>>(
        ctx, ctxb, B_ * LC_ * CTX_);
    k_transpose_x<<<dim3(HW_ / 32, C_ / 32, B_), dim3(32, 8), 0, stream>>>(x, xt);

    // Wvo_t = (Wv @ Wo)^T
    k_gemm<3><<<dim3(4, 6, 1), 256, 0, stream>>>(
        Wv_b, C_, 0, Wo_t, C_, 0, nullptr, Wvo_t, CTX_, C_, C_, 1.f);
    // Q = xt @ Wq + bq
    k_gemm<0><<<dim3(4, 256, 1), 256, 0, stream>>>(
        xt, C_, 0, Wq_t, C_, 0, bq, Qb, 0, C_, C_, 1.f);
    // K = ctx @ Wk + bk
    k_gemm<0><<<dim3(4, 32, 1), 256, 0, stream>>>(
        ctxb, CTX_, 0, Wk_t, CTX_, 0, bk, Kb, 0, C_, CTX_, 1.f);
    // V' = ctx @ Wvo + bvo  -> [B][C][Lc]
    k_gemm<1><<<dim3(4, 32, 1), 256, 0, stream>>>(
        ctxb, CTX_, 0, Wvo_t, CTX_, 0, bvo, Vt, 0, C_, CTX_, 1.f);
    // fused attention + residual
    k_flash<<<512, 512, 0, stream>>>(Qb, Kb, Vt, x, out);
}

// Round 8
// 251.100 us; speedup vs baseline: 1.1460x; 1.1460x over previous
//
#include <hip/hip_runtime.h>
#include <hip/hip_bf16.h>

typedef __bf16 bf16_t;
typedef bf16_t bf16x8 __attribute__((ext_vector_type(8)));
typedef bf16_t bf16x4 __attribute__((ext_vector_type(4)));
typedef float  f32x4  __attribute__((ext_vector_type(4)));

constexpr int B_ = 8, C_ = 512, HW_ = 4096, LC_ = 512, CTX_ = 768;

// ---------- prep kernels ----------

__global__ void k_transpose_w(const float* __restrict__ in, bf16_t* __restrict__ out,
                              int R, int Cc) {
    __shared__ float t[32][33];
    int r0 = blockIdx.x * 32, c0 = blockIdx.y * 32;
    int tx = threadIdx.x, ty = threadIdx.y;  // 32 x 8
#pragma unroll
    for (int i = 0; i < 4; ++i)
        t[ty + i * 8][tx] = in[(size_t)(r0 + ty + i * 8) * Cc + c0 + tx];
    __syncthreads();
#pragma unroll
    for (int i = 0; i < 4; ++i)
        out[(size_t)(c0 + ty + i * 8) * R + r0 + tx] = (bf16_t)t[tx][ty + i * 8];
}

__global__ void k_bvo(const float* __restrict__ bv, const float* __restrict__ Wo,
                      const float* __restrict__ bo, float* __restrict__ bvo) {
    int c = blockIdx.x * 256 + threadIdx.x;
    if (c >= C_) return;
    float s = bo[c];
    for (int m = 0; m < C_; ++m) s += bv[m] * Wo[(size_t)m * C_ + c];
    bvo[c] = s;
}

__global__ void k_f32_to_bf16(const float* __restrict__ in, bf16_t* __restrict__ out, int n) {
    int i = (blockIdx.x * 256 + threadIdx.x) * 4;
    if (i >= n) return;
    f32x4 v = *(const f32x4*)(in + i);
    bf16x4 w;
    w[0] = (bf16_t)v.x; w[1] = (bf16_t)v.y; w[2] = (bf16_t)v.z; w[3] = (bf16_t)v.w;
    *(bf16x4*)(out + i) = w;
}

// x [B][C][HW] f32  ->  xt [B][HW][C] bf16
__global__ void k_transpose_x(const float* __restrict__ x, bf16_t* __restrict__ xt) {
    __shared__ float t[32][33];
    int b = blockIdx.z;
    int p0 = blockIdx.x * 32, c0 = blockIdx.y * 32;
    const float* xb = x + (size_t)b * C_ * HW_;
    bf16_t* xtb = xt + (size_t)b * HW_ * C_;
    int tx = threadIdx.x, ty = threadIdx.y;  // 32 x 8
#pragma unroll
    for (int i = 0; i < 4; ++i) {
        int c = c0 + ty + i * 8;
        t[ty + i * 8][tx] = xb[(size_t)c * HW_ + p0 + tx];
    }
    __syncthreads();
#pragma unroll
    for (int i = 0; i < 4; ++i) {
        int p = p0 + ty + i * 8;
        xtb[(size_t)p * C_ + c0 + tx] = (bf16_t)t[tx][ty + i * 8];
    }
}

// ---------- projection GEMM (proven structure) ----------
// MODE 0: out bf16 [M][N], val = acc*scale + bias[n]
// MODE 1: out bf16 V^T layout: r -> (b=r>>9, l=r&511), out[b][n][l] = acc + bias[n]
// MODE 3: out bf16 transposed [N][Mtot], Mtot passed in sOut: out[n][m] = acc
template <int MODE>
__global__ __launch_bounds__(256) void k_gemm(
    const bf16_t* __restrict__ A, int lda, long sA,
    const bf16_t* __restrict__ Bt, int ldb, long sB,
    const float* __restrict__ bias,
    void* __restrict__ out_, long sOut,
    int N, int K, float scale) {
    __shared__ bf16_t lA[128 * 32];
    __shared__ bf16_t lB[128 * 32];
    const int z = blockIdx.z;
    A  += (size_t)z * sA;
    Bt += (size_t)z * sB;
    const int tid  = threadIdx.x;
    const int lane = tid & 63;
    const int wave = tid >> 6;
    const int wm = (wave >> 1) * 64, wn = (wave & 1) * 64;
    const int bm0 = blockIdx.y * 128, bn0 = blockIdx.x * 128;
    const int ar = lane & 15, kc = lane >> 4;

    auto lA3 = (__attribute__((address_space(3))) char*)&lA[0];
    auto lB3 = (__attribute__((address_space(3))) char*)&lB[0];

    f32x4 acc[4][4] = {};

    for (int k0 = 0; k0 < K; k0 += 32) {
        __syncthreads();
#pragma unroll
        for (int s = 0; s < 2; ++s) {
            int wchunk = wave * 2 + s;
            int id = wchunk * 64 + lane;
            int row = id >> 2, c4 = id & 3;
            __builtin_amdgcn_global_load_lds(
                (const __attribute__((address_space(1))) void*)
                    &A[(size_t)(bm0 + row) * lda + k0 + c4 * 8],
                (__attribute__((address_space(3))) void*)(lA3 + wchunk * 1024),
                16, 0, 0);
            __builtin_amdgcn_global_load_lds(
                (const __attribute__((address_space(1))) void*)
                    &Bt[(size_t)(bn0 + row) * ldb + k0 + c4 * 8],
                (__attribute__((address_space(3))) void*)(lB3 + wchunk * 1024),
                16, 0, 0);
        }
        __syncthreads();
        bf16x8 af[4], bfr[4];
#pragma unroll
        for (int f = 0; f < 4; ++f) {
            af[f]  = *(const bf16x8*)&lA[(wm + f * 16 + ar) * 32 + kc * 8];
            bfr[f] = *(const bf16x8*)&lB[(wn + f * 16 + ar) * 32 + kc * 8];
        }
#pragma unroll
        for (int fm = 0; fm < 4; ++fm)
#pragma unroll
            for (int fn = 0; fn < 4; ++fn)
                acc[fm][fn] = __builtin_amdgcn_mfma_f32_16x16x32_bf16(
                    af[fm], bfr[fn], acc[fm][fn], 0, 0, 0);
    }

    const int rj = (lane >> 4) * 4;
    const int cj = lane & 15;

#pragma unroll
    for (int fm = 0; fm < 4; ++fm) {
#pragma unroll
        for (int fn = 0; fn < 4; ++fn) {
            int r0 = bm0 + wm + fm * 16 + rj;
            int cc = bn0 + wn + fn * 16 + cj;
            if constexpr (MODE == 0) {
                bf16_t* out = (bf16_t*)out_ + (size_t)z * sOut;
                float bb = bias ? bias[cc] : 0.f;
#pragma unroll
                for (int j = 0; j < 4; ++j)
                    out[(size_t)(r0 + j) * N + cc] = (bf16_t)(acc[fm][fn][j] * scale + bb);
            } else if constexpr (MODE == 1) {
                bf16_t* out = (bf16_t*)out_;
                int b = r0 >> 9, l0 = r0 & 511;
                float bb = bias[cc];
                bf16x4 v;
#pragma unroll
                for (int j = 0; j < 4; ++j) v[j] = (bf16_t)(acc[fm][fn][j] + bb);
                *(bf16x4*)&out[(size_t)b * C_ * LC_ + (size_t)cc * LC_ + l0] = v;
            } else {  // MODE 3
                bf16_t* out = (bf16_t*)out_;
                bf16x4 v;
#pragma unroll
                for (int j = 0; j < 4; ++j) v[j] = (bf16_t)acc[fm][fn][j];
                *(bf16x4*)&out[(size_t)cc * sOut + r0] = v;
            }
        }
    }
}

// ---------- fused flash attention, LDS-staged K/V (m97 pattern) ----------
// Block: 32 q-rows x full Lc=512. 8 waves, wave w owns 64 lc-cols (QK) / 64 c-cols (PV).
// LDS: lQP 32KB (Q, then P; row-XOR-swizzled 16B chunks) + lKV 32KB (K/V step) + reduce.
// grid = 1024 blocks; z = bid&7 pins batch -> XCD so K/V stay L2-resident.
__global__ __launch_bounds__(512, 4) void k_flash(
    const bf16_t* __restrict__ Qb, const bf16_t* __restrict__ Kb,
    const bf16_t* __restrict__ Vt, const float* __restrict__ x,
    float* __restrict__ out) {
    __shared__ bf16_t lQP[32 * 512];   // 32 KB
    __shared__ bf16_t lKV[512 * 32];   // 32 KB: [512 rows][32 elems]
    __shared__ float redA[8][32];
    __shared__ float redB[8][32];

    const int bid = blockIdx.x;
    const int z = bid & 7;
    const int q0 = (bid >> 3) * 32;
    const int tid = threadIdx.x;
    const int lane = tid & 63;
    const int wave = tid >> 6;
    const int h = lane >> 4;     // 0..3 (k-chunk / row-subgroup)
    const int r15 = lane & 15;

    const bf16_t* Qz = Qb + ((size_t)z * HW_ + q0) * C_;
    const bf16_t* Kz = Kb + (size_t)z * LC_ * C_;
    const bf16_t* Vz = Vt + (size_t)z * C_ * LC_;

    auto lQ3 = (__attribute__((address_space(3))) char*)&lQP[0];
    auto lK3 = (__attribute__((address_space(3))) char*)&lKV[0];

    // ---- stage Q tile (32x512), source pre-swizzled so linear LDS dest = swizzled ----
#pragma unroll
    for (int s = 0; s < 4; ++s) {
        int row = wave * 4 + s;
        int c16 = (lane & 56) | ((lane ^ row) & 7);
        __builtin_amdgcn_global_load_lds(
            (const __attribute__((address_space(1))) void*)&Qz[(size_t)row * C_ + c16 * 8],
            (__attribute__((address_space(3))) void*)(lQ3 + row * 1024),
            16, 0, 0);
    }

    // ---- QK^T: acc[m][n] rows m*16+h*4+j, cols wave*64+n*16+r15 ----
    f32x4 acc[2][4] = {};
    for (int kk = 0; kk < 16; ++kk) {
        __syncthreads();   // prior step's lKV reads done (iter 0: pairs with Q-stage drain)
#pragma unroll
        for (int s = 0; s < 4; ++s) {
            int id = s * 512 + tid;          // 2048 x 16B chunks
            int row = id >> 2, c4 = id & 3;  // [512 lc][32 c]
            __builtin_amdgcn_global_load_lds(
                (const __attribute__((address_space(1))) void*)
                    &Kz[(size_t)row * C_ + kk * 32 + c4 * 8],
                (__attribute__((address_space(3))) void*)(lK3 + s * 8192 + wave * 1024),
                16, 0, 0);
        }
        __syncthreads();   // vmcnt drained -> lKV (and on iter 0, lQP) ready
        bf16x8 af[2], bfr[4];
#pragma unroll
        for (int m = 0; m < 2; ++m) {
            int row = m * 16 + r15;
            int c16 = kk * 4 + h;
            int sc = (c16 & 56) | ((c16 ^ row) & 7);
            af[m] = *(const bf16x8*)&lQP[row * 512 + sc * 8];
        }
#pragma unroll
        for (int n = 0; n < 4; ++n) {
            int lcrow = wave * 64 + n * 16 + r15;
            bfr[n] = *(const bf16x8*)&lKV[lcrow * 32 + h * 8];
        }
#pragma unroll
        for (int m = 0; m < 2; ++m)
#pragma unroll
            for (int n = 0; n < 4; ++n)
                acc[m][n] = __builtin_amdgcn_mfma_f32_16x16x32_bf16(
                    af[m], bfr[n], acc[m][n], 0, 0, 0);
    }

    // ---- softmax over full rows (512 cols across 8 waves) ----
    const float scale = 0.044194173824159216f;  // 512^-0.5
    float M[2][4], inv[2][4];
#pragma unroll
    for (int m = 0; m < 2; ++m)
#pragma unroll
        for (int j = 0; j < 4; ++j) {
            float v = fmaxf(fmaxf(acc[m][0][j], acc[m][1][j]),
                            fmaxf(acc[m][2][j], acc[m][3][j]));
#pragma unroll
            for (int o = 1; o < 16; o <<= 1) v = fmaxf(v, __shfl_xor(v, o));
            if (r15 == 0) redA[wave][m * 16 + h * 4 + j] = v;
        }
    __syncthreads();   // also: all lQP reads of Q complete before this point
#pragma unroll
    for (int m = 0; m < 2; ++m)
#pragma unroll
        for (int j = 0; j < 4; ++j) {
            int row = m * 16 + h * 4 + j;
            float v = redA[0][row];
#pragma unroll
            for (int w = 1; w < 8; ++w) v = fmaxf(v, redA[w][row]);
            M[m][j] = v;
        }
#pragma unroll
    for (int m = 0; m < 2; ++m)
#pragma unroll
        for (int j = 0; j < 4; ++j) {
            float s = 0.f;
#pragma unroll
            for (int n = 0; n < 4; ++n) {
                float e = __expf((acc[m][n][j] - M[m][j]) * scale);
                acc[m][n][j] = e;
                s += e;
            }
#pragma unroll
            for (int o = 1; o < 16; o <<= 1) s += __shfl_xor(s, o);
            if (r15 == 0) redB[wave][m * 16 + h * 4 + j] = s;
        }
    __syncthreads();
#pragma unroll
    for (int m = 0; m < 2; ++m)
#pragma unroll
        for (int j = 0; j < 4; ++j) {
            int row = m * 16 + h * 4 + j;
            float s = redB[0][row];
#pragma unroll
            for (int w = 1; w < 8; ++w) s += redB[w][row];
            inv[m][j] = 1.f / s;
        }

    // ---- write P (bf16, swizzled) into lQP (Q dead) ----
#pragma unroll
    for (int m = 0; m < 2; ++m)
#pragma unroll
        for (int j = 0; j < 4; ++j) {
            int row = m * 16 + h * 4 + j;
#pragma unroll
            for (int n = 0; n < 4; ++n) {
                int col = wave * 64 + n * 16 + r15;
                int c16 = col >> 3;
                int sc = (c16 & 56) | ((c16 ^ row) & 7);
                lQP[row * 512 + sc * 8 + (col & 7)] = (bf16_t)(acc[m][n][j] * inv[m][j]);
            }
        }

    // ---- PV: O[q][c] = sum_lc P[q][lc] * Vt[c][lc]; wave owns 64 c-cols ----
    f32x4 oacc[2][4] = {};
    for (int kk = 0; kk < 16; ++kk) {
        __syncthreads();   // P-writes (iter 0) / prior lKV reads done
#pragma unroll
        for (int s = 0; s < 4; ++s) {
            int id = s * 512 + tid;
            int row = id >> 2, c4 = id & 3;  // [512 c][32 lc]
            __builtin_amdgcn_global_load_lds(
                (const __attribute__((address_space(1))) void*)
                    &Vz[(size_t)row * LC_ + kk * 32 + c4 * 8],
                (__attribute__((address_space(3))) void*)(lK3 + s * 8192 + wave * 1024),
                16, 0, 0);
        }
        __syncthreads();
        bf16x8 pf[2], vf[4];
#pragma unroll
        for (int m = 0; m < 2; ++m) {
            int row = m * 16 + r15;
            int c16 = kk * 4 + h;
            int sc = (c16 & 56) | ((c16 ^ row) & 7);
            pf[m] = *(const bf16x8*)&lQP[row * 512 + sc * 8];
        }
#pragma unroll
        for (int n = 0; n < 4; ++n) {
            int crow = wave * 64 + n * 16 + r15;
            vf[n] = *(const bf16x8*)&lKV[crow * 32 + h * 8];
        }
#pragma unroll
        for (int m = 0; m < 2; ++m)
#pragma unroll
            for (int n = 0; n < 4; ++n)
                oacc[m][n] = __builtin_amdgcn_mfma_f32_16x16x32_bf16(
                    pf[m], vf[n], oacc[m][n], 0, 0, 0);
    }

    // ---- epilogue: out[c][hw] = O + x[c][hw] ----
    float* oz = out + (size_t)z * C_ * HW_;
    const float* xz = x + (size_t)z * C_ * HW_;
#pragma unroll
    for (int m = 0; m < 2; ++m)
#pragma unroll
        for (int n = 0; n < 4; ++n) {
            int r0 = q0 + m * 16 + h * 4;
            int cc = wave * 64 + n * 16 + r15;
            f32x4 xv = *(const f32x4*)&xz[(size_t)cc * HW_ + r0];
            f32x4 o;
#pragma unroll
            for (int j = 0; j < 4; ++j) o[j] = oacc[m][n][j] + xv[j];
            *(f32x4*)&oz[(size_t)cc * HW_ + r0] = o;
        }
}

extern "C" void kernel_launch(void* const* d_in, const int* in_sizes, int n_in,
                              void* d_out, int out_size, void* d_ws, size_t ws_size,
                              hipStream_t stream) {
    (void)in_sizes; (void)n_in; (void)out_size; (void)ws_size;
    const float* x   = (const float*)d_in[0];
    const float* ctx = (const float*)d_in[1];
    const float* Wq  = (const float*)d_in[2];
    const float* bq  = (const float*)d_in[3];
    const float* Wk  = (const float*)d_in[4];
    const float* bk  = (const float*)d_in[5];
    const float* Wv  = (const float*)d_in[6];
    const float* bv  = (const float*)d_in[7];
    const float* Wo  = (const float*)d_in[8];
    const float* bo  = (const float*)d_in[9];
    float* out = (float*)d_out;

    char* ws = (char*)d_ws;
    size_t off = 0;
    auto alloc = [&](size_t bytes) {
        char* p = ws + off;
        off += (bytes + 255) & ~(size_t)255;
        return p;
    };
    bf16_t* Wq_t  = (bf16_t*)alloc((size_t)C_ * C_ * 2);
    bf16_t* Wk_t  = (bf16_t*)alloc((size_t)C_ * CTX_ * 2);
    bf16_t* Wvo_t = (bf16_t*)alloc((size_t)C_ * CTX_ * 2);
    bf16_t* Wv_b  = (bf16_t*)alloc((size_t)CTX_ * C_ * 2);
    bf16_t* Wo_t  = (bf16_t*)alloc((size_t)C_ * C_ * 2);
    float*  bvo   = (float*)alloc((size_t)C_ * 4);
    bf16_t* ctxb  = (bf16_t*)alloc((size_t)B_ * LC_ * CTX_ * 2);
    bf16_t* xt    = (bf16_t*)alloc((size_t)B_ * HW_ * C_ * 2);
    bf16_t* Qb    = (bf16_t*)alloc((size_t)B_ * HW_ * C_ * 2);
    bf16_t* Kb    = (bf16_t*)alloc((size_t)B_ * LC_ * C_ * 2);
    bf16_t* Vt    = (bf16_t*)alloc((size_t)B_ * C_ * LC_ * 2);

    // weight prep
    k_transpose_w<<<dim3(C_ / 32, C_ / 32), dim3(32, 8), 0, stream>>>(Wq, Wq_t, C_, C_);
    k_transpose_w<<<dim3(CTX_ / 32, C_ / 32), dim3(32, 8), 0, stream>>>(Wk, Wk_t, CTX_, C_);
    k_transpose_w<<<dim3(C_ / 32, C_ / 32), dim3(32, 8), 0, stream>>>(Wo, Wo_t, C_, C_);
    k_f32_to_bf16<<<(CTX_ * C_ / 4 + 255) / 256, 256, 0, stream>>>(Wv, Wv_b, CTX_ * C_);
    k_bvo<<<2, 256, 0, stream>>>(bv, Wo, bo, bvo);
    k_f32_to_bf16<<<(B_ * LC_ * CTX_ / 4 + 255) / 256, 256, 0, stream>>>(
        ctx, ctxb, B_ * LC_ * CTX_);
    k_transpose_x<<<dim3(HW_ / 32, C_ / 32, B_), dim3(32, 8), 0, stream>>>(x, xt);

    // Wvo_t = (Wv @ Wo)^T
    k_gemm<3><<<dim3(4, 6, 1), 256, 0, stream>>>(
        Wv_b, C_, 0, Wo_t, C_, 0, nullptr, Wvo_t, CTX_, C_, C_, 1.f);
    // Q = xt @ Wq + bq
    k_gemm<0><<<dim3(4, 256, 1), 256, 0, stream>>>(
        xt, C_, 0, Wq_t, C_, 0, bq, Qb, 0, C_, C_, 1.f);
    // K = ctx @ Wk + bk
    k_gemm<0><<<dim3(4, 32, 1), 256, 0, stream>>>(
        ctxb, CTX_, 0, Wk_t, CTX_, 0, bk, Kb, 0, C_, CTX_, 1.f);
    // V' = ctx @ Wvo + bvo  -> [B][C][Lc]
    k_gemm<1><<<dim3(4, 32, 1), 256, 0, stream>>>(
        ctxb, CTX_, 0, Wvo_t, CTX_, 0, bvo, Vt, 0, C_, CTX_, 1.f);
    // fused attention + residual
    k_flash<<<1024, 512, 0, stream>>>(Qb, Kb, Vt, x, out);
}

// Round 9
// 222.942 us; speedup vs baseline: 1.2907x; 1.1263x over previous
//
#include <hip/hip_runtime.h>
#include <hip/hip_bf16.h>

typedef __bf16 bf16_t;
typedef bf16_t bf16x8 __attribute__((ext_vector_type(8)));
typedef bf16_t bf16x4 __attribute__((ext_vector_type(4)));
typedef float  f32x4  __attribute__((ext_vector_type(4)));

constexpr int B_ = 8, C_ = 512, HW_ = 4096, LC_ = 512, CTX_ = 768;

// ---------- prep kernels ----------

__global__ void k_transpose_w(const float* __restrict__ in, bf16_t* __restrict__ out,
                              int R, int Cc) {
    __shared__ float t[32][33];
    int r0 = blockIdx.x * 32, c0 = blockIdx.y * 32;
    int tx = threadIdx.x, ty = threadIdx.y;  // 32 x 8
#pragma unroll
    for (int i = 0; i < 4; ++i)
        t[ty + i * 8][tx] = in[(size_t)(r0 + ty + i * 8) * Cc + c0 + tx];
    __syncthreads();
#pragma unroll
    for (int i = 0; i < 4; ++i)
        out[(size_t)(c0 + ty + i * 8) * R + r0 + tx] = (bf16_t)t[tx][ty + i * 8];
}

__global__ void k_bvo(const float* __restrict__ bv, const float* __restrict__ Wo,
                      const float* __restrict__ bo, float* __restrict__ bvo) {
    int c = blockIdx.x * 256 + threadIdx.x;
    if (c >= C_) return;
    float s = bo[c];
    for (int m = 0; m < C_; ++m) s += bv[m] * Wo[(size_t)m * C_ + c];
    bvo[c] = s;
}

__global__ void k_f32_to_bf16(const float* __restrict__ in, bf16_t* __restrict__ out, int n) {
    int i = (blockIdx.x * 256 + threadIdx.x) * 4;
    if (i >= n) return;
    f32x4 v = *(const f32x4*)(in + i);
    bf16x4 w;
    w[0] = (bf16_t)v.x; w[1] = (bf16_t)v.y; w[2] = (bf16_t)v.z; w[3] = (bf16_t)v.w;
    *(bf16x4*)(out + i) = w;
}

// x [B][C][HW] f32  ->  xt [B][HW][C] bf16
__global__ void k_transpose_x(const float* __restrict__ x, bf16_t* __restrict__ xt) {
    __shared__ float t[32][33];
    int b = blockIdx.z;
    int p0 = blockIdx.x * 32, c0 = blockIdx.y * 32;
    const float* xb = x + (size_t)b * C_ * HW_;
    bf16_t* xtb = xt + (size_t)b * HW_ * C_;
    int tx = threadIdx.x, ty = threadIdx.y;  // 32 x 8
#pragma unroll
    for (int i = 0; i < 4; ++i) {
        int c = c0 + ty + i * 8;
        t[ty + i * 8][tx] = xb[(size_t)c * HW_ + p0 + tx];
    }
    __syncthreads();
#pragma unroll
    for (int i = 0; i < 4; ++i) {
        int p = p0 + ty + i * 8;
        xtb[(size_t)p * C_ + c0 + tx] = (bf16_t)t[tx][ty + i * 8];
    }
}

// ---------- projection GEMM (proven structure) ----------
// MODE 0: out bf16 [M][N], val = acc*scale + bias[n]
// MODE 1: out bf16 V^T layout: r -> (b=r>>9, l=r&511), out[b][n][l] = acc + bias[n]
// MODE 3: out bf16 transposed [N][Mtot], Mtot passed in sOut: out[n][m] = acc
template <int MODE>
__global__ __launch_bounds__(256) void k_gemm(
    const bf16_t* __restrict__ A, int lda, long sA,
    const bf16_t* __restrict__ Bt, int ldb, long sB,
    const float* __restrict__ bias,
    void* __restrict__ out_, long sOut,
    int N, int K, float scale) {
    __shared__ bf16_t lA[128 * 32];
    __shared__ bf16_t lB[128 * 32];
    const int z = blockIdx.z;
    A  += (size_t)z * sA;
    Bt += (size_t)z * sB;
    const int tid  = threadIdx.x;
    const int lane = tid & 63;
    const int wave = tid >> 6;
    const int wm = (wave >> 1) * 64, wn = (wave & 1) * 64;
    const int bm0 = blockIdx.y * 128, bn0 = blockIdx.x * 128;
    const int ar = lane & 15, kc = lane >> 4;

    auto lA3 = (__attribute__((address_space(3))) char*)&lA[0];
    auto lB3 = (__attribute__((address_space(3))) char*)&lB[0];

    f32x4 acc[4][4] = {};

    for (int k0 = 0; k0 < K; k0 += 32) {
        __syncthreads();
#pragma unroll
        for (int s = 0; s < 2; ++s) {
            int wchunk = wave * 2 + s;
            int id = wchunk * 64 + lane;
            int row = id >> 2, c4 = id & 3;
            __builtin_amdgcn_global_load_lds(
                (const __attribute__((address_space(1))) void*)
                    &A[(size_t)(bm0 + row) * lda + k0 + c4 * 8],
                (__attribute__((address_space(3))) void*)(lA3 + wchunk * 1024),
                16, 0, 0);
            __builtin_amdgcn_global_load_lds(
                (const __attribute__((address_space(1))) void*)
                    &Bt[(size_t)(bn0 + row) * ldb + k0 + c4 * 8],
                (__attribute__((address_space(3))) void*)(lB3 + wchunk * 1024),
                16, 0, 0);
        }
        __syncthreads();
        bf16x8 af[4], bfr[4];
#pragma unroll
        for (int f = 0; f < 4; ++f) {
            af[f]  = *(const bf16x8*)&lA[(wm + f * 16 + ar) * 32 + kc * 8];
            bfr[f] = *(const bf16x8*)&lB[(wn + f * 16 + ar) * 32 + kc * 8];
        }
#pragma unroll
        for (int fm = 0; fm < 4; ++fm)
#pragma unroll
            for (int fn = 0; fn < 4; ++fn)
                acc[fm][fn] = __builtin_amdgcn_mfma_f32_16x16x32_bf16(
                    af[fm], bfr[fn], acc[fm][fn], 0, 0, 0);
    }

    const int rj = (lane >> 4) * 4;
    const int cj = lane & 15;

#pragma unroll
    for (int fm = 0; fm < 4; ++fm) {
#pragma unroll
        for (int fn = 0; fn < 4; ++fn) {
            int r0 = bm0 + wm + fm * 16 + rj;
            int cc = bn0 + wn + fn * 16 + cj;
            if constexpr (MODE == 0) {
                bf16_t* out = (bf16_t*)out_ + (size_t)z * sOut;
                float bb = bias ? bias[cc] : 0.f;
#pragma unroll
                for (int j = 0; j < 4; ++j)
                    out[(size_t)(r0 + j) * N + cc] = (bf16_t)(acc[fm][fn][j] * scale + bb);
            } else if constexpr (MODE == 1) {
                bf16_t* out = (bf16_t*)out_;
                int b = r0 >> 9, l0 = r0 & 511;
                float bb = bias[cc];
                bf16x4 v;
#pragma unroll
                for (int j = 0; j < 4; ++j) v[j] = (bf16_t)(acc[fm][fn][j] + bb);
                *(bf16x4*)&out[(size_t)b * C_ * LC_ + (size_t)cc * LC_ + l0] = v;
            } else {  // MODE 3
                bf16_t* out = (bf16_t*)out_;
                bf16x4 v;
#pragma unroll
                for (int j = 0; j < 4; ++j) v[j] = (bf16_t)acc[fm][fn][j];
                *(bf16x4*)&out[(size_t)cc * sOut + r0] = v;
            }
        }
    }
}

// ---------- fused Q-proj + flash attention ----------
// Block: 64 q-rows. Three streamed-GEMM phases sharing one structure:
//   P1: Q = xt_tile(LDS) @ Wq_t + bq   (stream Wq_t)
//   P2: S = Q(LDS) @ K^T               (stream Kb)
//   P3: O = P(LDS) @ V                 (stream Vt)
// lQP holds xt -> Q -> P (row-swizzled); lKV is a 2x32KB double-buffered
// stream tile staged via global_load_lds, prefetched one step ahead.
// 8 waves as 2(M)x4(N): wave = 32 q-rows x 128 cols. grid=512, z=bid&7 XCD-pin.
__global__ __launch_bounds__(512, 2) void k_flash(
    const bf16_t* __restrict__ xt, const bf16_t* __restrict__ Wq_t,
    const float* __restrict__ bq,
    const bf16_t* __restrict__ Kb, const bf16_t* __restrict__ Vt,
    const float* __restrict__ x, float* __restrict__ out) {
    __shared__ bf16_t lQP[64 * 512];       // 64 KB
    __shared__ bf16_t lKV[2][512 * 32];    // 2 x 32 KB
    __shared__ float redA[4][64];
    __shared__ float redB[4][64];

    const int bid = blockIdx.x;
    const int z = bid & 7;
    const int q0 = (bid >> 3) * 64;
    const int tid = threadIdx.x;
    const int lane = tid & 63;
    const int wave = tid >> 6;
    const int wm2 = wave >> 2;   // 0..1 : 32-q-row group
    const int wn4 = wave & 3;    // 0..3 : 128-col group
    const int h = lane >> 4;     // 0..3
    const int r15 = lane & 15;

    const bf16_t* Az = xt + ((size_t)z * HW_ + q0) * C_;
    const bf16_t* Kz = Kb + (size_t)z * LC_ * C_;
    const bf16_t* Vz = Vt + (size_t)z * C_ * LC_;

    auto lQ3 = (__attribute__((address_space(3))) char*)&lQP[0];
    auto lK3 = (__attribute__((address_space(3))) char*)&lKV[0][0];

    // stage one [512 rows][32 k] bf16 tile (32 KB) into lKV[b]; source slot
    // pre-swizzled (c4 ^ row&3) so swizzled-read is conflict-free.
    auto STAGE = [&](int b, const bf16_t* __restrict__ Bsrc, int kk) {
#pragma unroll
        for (int s = 0; s < 4; ++s) {
            int id = s * 512 + tid;
            int row = id >> 2, c4 = id & 3;
            int c4s = c4 ^ (row & 3);
            __builtin_amdgcn_global_load_lds(
                (const __attribute__((address_space(1))) void*)
                    &Bsrc[(size_t)row * 512 + kk * 32 + c4s * 8],
                (__attribute__((address_space(3))) void*)
                    (lK3 + b * 32768 + s * 8192 + wave * 1024),
                16, 0, 0);
        }
    };

    // ---- stage xt tile [64][512] into lQP (source pre-swizzled) ----
#pragma unroll
    for (int t = 0; t < 8; ++t) {
        int row = wave * 8 + t;
        int c16 = (lane & 56) | ((lane ^ row) & 7);
        __builtin_amdgcn_global_load_lds(
            (const __attribute__((address_space(1))) void*)&Az[(size_t)row * C_ + c16 * 8],
            (__attribute__((address_space(3))) void*)(lQ3 + row * 1024),
            16, 0, 0);
    }
    STAGE(0, Wq_t, 0);
    __syncthreads();

    // ---- phase 1: Q = xt @ Wq_t  (acc rows wm2*32+m*16+h*4+j, cols wn4*128+n*16+r15)
    f32x4 acc[2][8] = {};
    for (int kk = 0; kk < 16; ++kk) {
        if (kk < 15) STAGE((kk + 1) & 1, Wq_t, kk + 1);
        else         STAGE(0, Kz, 0);
        bf16x8 af[2], bfr[8];
#pragma unroll
        for (int m = 0; m < 2; ++m) {
            int row = wm2 * 32 + m * 16 + r15;
            int c16 = kk * 4 + h;
            int sc = (c16 & 56) | ((c16 ^ row) & 7);
            af[m] = *(const bf16x8*)&lQP[row * 512 + sc * 8];
        }
        const bf16_t* lb = &lKV[kk & 1][0];
#pragma unroll
        for (int n = 0; n < 8; ++n) {
            int row = wn4 * 128 + n * 16 + r15;
            bfr[n] = *(const bf16x8*)&lb[row * 32 + (h ^ (row & 3)) * 8];
        }
#pragma unroll
        for (int m = 0; m < 2; ++m)
#pragma unroll
            for (int n = 0; n < 8; ++n)
                acc[m][n] = __builtin_amdgcn_mfma_f32_16x16x32_bf16(
                    af[m], bfr[n], acc[m][n], 0, 0, 0);
        __syncthreads();
    }

    // ---- write Q (+bq) into lQP, swizzled (xt dead) ----
    {
        float bqv[8];
#pragma unroll
        for (int n = 0; n < 8; ++n) bqv[n] = bq[wn4 * 128 + n * 16 + r15];
#pragma unroll
        for (int m = 0; m < 2; ++m)
#pragma unroll
            for (int j = 0; j < 4; ++j) {
                int row = wm2 * 32 + m * 16 + h * 4 + j;
#pragma unroll
                for (int n = 0; n < 8; ++n) {
                    int col = wn4 * 128 + n * 16 + r15;
                    int c16 = col >> 3;
                    int sc = (c16 & 56) | ((c16 ^ row) & 7);
                    lQP[row * 512 + sc * 8 + (col & 7)] = (bf16_t)(acc[m][n][j] + bqv[n]);
                }
            }
    }
    __syncthreads();

    // ---- phase 2: S = Q @ K^T ----
#pragma unroll
    for (int m = 0; m < 2; ++m)
#pragma unroll
        for (int n = 0; n < 8; ++n) acc[m][n] = (f32x4)0.f;
    for (int kk = 0; kk < 16; ++kk) {
        if (kk < 15) STAGE((kk + 1) & 1, Kz, kk + 1);
        else         STAGE(0, Vz, 0);
        bf16x8 af[2], bfr[8];
#pragma unroll
        for (int m = 0; m < 2; ++m) {
            int row = wm2 * 32 + m * 16 + r15;
            int c16 = kk * 4 + h;
            int sc = (c16 & 56) | ((c16 ^ row) & 7);
            af[m] = *(const bf16x8*)&lQP[row * 512 + sc * 8];
        }
        const bf16_t* lb = &lKV[kk & 1][0];
#pragma unroll
        for (int n = 0; n < 8; ++n) {
            int row = wn4 * 128 + n * 16 + r15;
            bfr[n] = *(const bf16x8*)&lb[row * 32 + (h ^ (row & 3)) * 8];
        }
#pragma unroll
        for (int m = 0; m < 2; ++m)
#pragma unroll
            for (int n = 0; n < 8; ++n)
                acc[m][n] = __builtin_amdgcn_mfma_f32_16x16x32_bf16(
                    af[m], bfr[n], acc[m][n], 0, 0, 0);
        __syncthreads();
    }

    // ---- softmax over full rows (512 lc across the 4 wn4 waves per row group) ----
    const float scale = 0.044194173824159216f;  // 512^-0.5
    float M[2][4], inv[2][4];
#pragma unroll
    for (int m = 0; m < 2; ++m)
#pragma unroll
        for (int j = 0; j < 4; ++j) {
            float v = -1e30f;
#pragma unroll
            for (int n = 0; n < 8; ++n) v = fmaxf(v, acc[m][n][j]);
#pragma unroll
            for (int o = 1; o < 16; o <<= 1) v = fmaxf(v, __shfl_xor(v, o));
            if (r15 == 0) redA[wn4][wm2 * 32 + m * 16 + h * 4 + j] = v;
        }
    __syncthreads();
#pragma unroll
    for (int m = 0; m < 2; ++m)
#pragma unroll
        for (int j = 0; j < 4; ++j) {
            int row = wm2 * 32 + m * 16 + h * 4 + j;
            M[m][j] = fmaxf(fmaxf(redA[0][row], redA[1][row]),
                            fmaxf(redA[2][row], redA[3][row]));
        }
#pragma unroll
    for (int m = 0; m < 2; ++m)
#pragma unroll
        for (int j = 0; j < 4; ++j) {
            float s = 0.f;
#pragma unroll
            for (int n = 0; n < 8; ++n) {
                float e = __expf((acc[m][n][j] - M[m][j]) * scale);
                acc[m][n][j] = e;
                s += e;
            }
#pragma unroll
            for (int o = 1; o < 16; o <<= 1) s += __shfl_xor(s, o);
            if (r15 == 0) redB[wn4][wm2 * 32 + m * 16 + h * 4 + j] = s;
        }
    __syncthreads();
#pragma unroll
    for (int m = 0; m < 2; ++m)
#pragma unroll
        for (int j = 0; j < 4; ++j) {
            int row = wm2 * 32 + m * 16 + h * 4 + j;
            inv[m][j] = 1.f / (redB[0][row] + redB[1][row] +
                               redB[2][row] + redB[3][row]);
        }
    __syncthreads();   // all phase-2 Q reads of lQP done; reuse as P

    // ---- write P (bf16, swizzled) into lQP ----
#pragma unroll
    for (int m = 0; m < 2; ++m)
#pragma unroll
        for (int j = 0; j < 4; ++j) {
            int row = wm2 * 32 + m * 16 + h * 4 + j;
#pragma unroll
            for (int n = 0; n < 8; ++n) {
                int col = wn4 * 128 + n * 16 + r15;
                int c16 = col >> 3;
                int sc = (c16 & 56) | ((c16 ^ row) & 7);
                lQP[row * 512 + sc * 8 + (col & 7)] = (bf16_t)(acc[m][n][j] * inv[m][j]);
            }
        }
    __syncthreads();

    // ---- phase 3: O = P @ V ----
    f32x4 oacc[2][8] = {};
    for (int kk = 0; kk < 16; ++kk) {
        if (kk < 15) STAGE((kk + 1) & 1, Vz, kk + 1);
        bf16x8 pf[2], vf[8];
#pragma unroll
        for (int m = 0; m < 2; ++m) {
            int row = wm2 * 32 + m * 16 + r15;
            int c16 = kk * 4 + h;
            int sc = (c16 & 56) | ((c16 ^ row) & 7);
            pf[m] = *(const bf16x8*)&lQP[row * 512 + sc * 8];
        }
        const bf16_t* lb = &lKV[kk & 1][0];
#pragma unroll
        for (int n = 0; n < 8; ++n) {
            int row = wn4 * 128 + n * 16 + r15;
            vf[n] = *(const bf16x8*)&lb[row * 32 + (h ^ (row & 3)) * 8];
        }
#pragma unroll
        for (int m = 0; m < 2; ++m)
#pragma unroll
            for (int n = 0; n < 8; ++n)
                oacc[m][n] = __builtin_amdgcn_mfma_f32_16x16x32_bf16(
                    pf[m], vf[n], oacc[m][n], 0, 0, 0);
        if (kk < 15) __syncthreads();
    }

    // ---- epilogue: out[c][hw] = O + x[c][hw] ----
    float* oz = out + (size_t)z * C_ * HW_;
    const float* xz = x + (size_t)z * C_ * HW_;
#pragma unroll
    for (int m = 0; m < 2; ++m)
#pragma unroll
        for (int n = 0; n < 8; ++n) {
            int r0 = q0 + wm2 * 32 + m * 16 + h * 4;
            int cc = wn4 * 128 + n * 16 + r15;
            f32x4 xv = *(const f32x4*)&xz[(size_t)cc * HW_ + r0];
            f32x4 o;
#pragma unroll
            for (int j = 0; j < 4; ++j) o[j] = oacc[m][n][j] + xv[j];
            *(f32x4*)&oz[(size_t)cc * HW_ + r0] = o;
        }
}

extern "C" void kernel_launch(void* const* d_in, const int* in_sizes, int n_in,
                              void* d_out, int out_size, void* d_ws, size_t ws_size,
                              hipStream_t stream) {
    (void)in_sizes; (void)n_in; (void)out_size; (void)ws_size;
    const float* x   = (const float*)d_in[0];
    const float* ctx = (const float*)d_in[1];
    const float* Wq  = (const float*)d_in[2];
    const float* bq  = (const float*)d_in[3];
    const float* Wk  = (const float*)d_in[4];
    const float* bk  = (const float*)d_in[5];
    const float* Wv  = (const float*)d_in[6];
    const float* bv  = (const float*)d_in[7];
    const float* Wo  = (const float*)d_in[8];
    const float* bo  = (const float*)d_in[9];
    float* out = (float*)d_out;

    char* ws = (char*)d_ws;
    size_t off = 0;
    auto alloc = [&](size_t bytes) {
        char* p = ws + off;
        off += (bytes + 255) & ~(size_t)255;
        return p;
    };
    bf16_t* Wq_t  = (bf16_t*)alloc((size_t)C_ * C_ * 2);
    bf16_t* Wk_t  = (bf16_t*)alloc((size_t)C_ * CTX_ * 2);
    bf16_t* Wvo_t = (bf16_t*)alloc((size_t)C_ * CTX_ * 2);
    bf16_t* Wv_b  = (bf16_t*)alloc((size_t)CTX_ * C_ * 2);
    bf16_t* Wo_t  = (bf16_t*)alloc((size_t)C_ * C_ * 2);
    float*  bvo   = (float*)alloc((size_t)C_ * 4);
    bf16_t* ctxb  = (bf16_t*)alloc((size_t)B_ * LC_ * CTX_ * 2);
    bf16_t* xt    = (bf16_t*)alloc((size_t)B_ * HW_ * C_ * 2);
    bf16_t* Kb    = (bf16_t*)alloc((size_t)B_ * LC_ * C_ * 2);
    bf16_t* Vt    = (bf16_t*)alloc((size_t)B_ * C_ * LC_ * 2);

    // weight prep
    k_transpose_w<<<dim3(C_ / 32, C_ / 32), dim3(32, 8), 0, stream>>>(Wq, Wq_t, C_, C_);
    k_transpose_w<<<dim3(CTX_ / 32, C_ / 32), dim3(32, 8), 0, stream>>>(Wk, Wk_t, CTX_, C_);
    k_transpose_w<<<dim3(C_ / 32, C_ / 32), dim3(32, 8), 0, stream>>>(Wo, Wo_t, C_, C_);
    k_f32_to_bf16<<<(CTX_ * C_ / 4 + 255) / 256, 256, 0, stream>>>(Wv, Wv_b, CTX_ * C_);
    k_bvo<<<2, 256, 0, stream>>>(bv, Wo, bo, bvo);
    k_f32_to_bf16<<<(B_ * LC_ * CTX_ / 4 + 255) / 256, 256, 0, stream>>>(
        ctx, ctxb, B_ * LC_ * CTX_);
    k_transpose_x<<<dim3(HW_ / 32, C_ / 32, B_), dim3(32, 8), 0, stream>>>(x, xt);

    // Wvo_t = (Wv @ Wo)^T
    k_gemm<3><<<dim3(4, 6, 1), 256, 0, stream>>>(
        Wv_b, C_, 0, Wo_t, C_, 0, nullptr, Wvo_t, CTX_, C_, C_, 1.f);
    // K = ctx @ Wk + bk
    k_gemm<0><<<dim3(4, 32, 1), 256, 0, stream>>>(
        ctxb, CTX_, 0, Wk_t, CTX_, 0, bk, Kb, 0, C_, CTX_, 1.f);
    // V' = ctx @ Wvo + bvo  -> [B][C][Lc]
    k_gemm<1><<<dim3(4, 32, 1), 256, 0, stream>>>(
        ctxb, CTX_, 0, Wvo_t, CTX_, 0, bvo, Vt, 0, C_, CTX_, 1.f);
    // fused Q-projection + attention + residual
    k_flash<<<512, 512, 0, stream>>>(xt, Wq_t, bq, Kb, Vt, x, out);
}